// Round 2
// baseline (58.197 us; speedup 1.0000x reference)
//
#include <hip/hip_runtime.h>

// Problem constants (from reference): B=32, T=4096, D=512, R=64,
// LOCAL_SIZE=20, SAMPLING_RATE=10, LN_EPS=1e-5
static constexpr int Bsz   = 32;
static constexpr int Tlen  = 4096;
static constexpr int Ddim  = 512;
static constexpr int Rdim  = 64;
static constexpr int NSAMP = 408;   // len(range(0, 4076, 10))
static constexpr int NPRES = 20;
static constexpr int NROWS = NSAMP + NPRES;  // 428

// Monotone float<->uint order-preserving encoding for deterministic atomicMax.
__device__ __forceinline__ unsigned f2ord(float x) {
  unsigned u = __float_as_uint(x);
  return (u & 0x80000000u) ? ~u : (u | 0x80000000u);
}
__device__ __forceinline__ float ord2f(unsigned v) {
  return __uint_as_float((v & 0x80000000u) ? (v & 0x7FFFFFFFu) : ~v);
}

// K1: for each needed timestep row, compute cf = LN(ReLU(x @ w_red + b_red)).
// 16 rows per block (4 waves x 4 rows each). Lane r owns output channel r.
__global__ __launch_bounds__(256) void k1_cf(
    const float* __restrict__ obs, const float* __restrict__ wred,
    const float* __restrict__ bred, const float* __restrict__ gred,
    const float* __restrict__ betared,
    unsigned* __restrict__ pp_u,      // [B][64] ordered-uint running max
    float* __restrict__ present,      // [B][20][64]
    float* __restrict__ out_now)      // [B][64]
{
  __shared__ float xs[16][Ddim];      // 32 KB
  const int b    = blockIdx.y;
  const int base = blockIdx.x * 16;
  const int tid  = threadIdx.x;

  // Stage 16 input rows (clamp overhang rows to the last valid row; the
  // duplicate work recomputes identical values -> benign rewrites).
  for (int p = 0; p < 8; ++p) {
    int idx = p * 256 + tid;          // 0..2047 = 16 rows * 128 float4
    int lr  = idx >> 7;
    int c   = idx & 127;
    int gr  = min(base + lr, NROWS - 1);
    int t   = (gr < NSAMP) ? gr * 10 : (Tlen - NPRES) + (gr - NSAMP);
    const float4* src = (const float4*)(obs + ((size_t)b * Tlen + t) * Ddim);
    *(float4*)&xs[lr][c * 4] = src[c];
  }
  __syncthreads();

  const int wid  = tid >> 6;
  const int lane = tid & 63;
  const int lr0  = wid * 4;

  float acc[4] = {0.f, 0.f, 0.f, 0.f};
  for (int d = 0; d < Ddim; d += 4) {
    float w0 = wred[(d + 0) * 64 + lane];
    float w1 = wred[(d + 1) * 64 + lane];
    float w2 = wred[(d + 2) * 64 + lane];
    float w3 = wred[(d + 3) * 64 + lane];
#pragma unroll
    for (int rr = 0; rr < 4; ++rr) {
      float4 xv = *(const float4*)&xs[lr0 + rr][d];
      acc[rr] = fmaf(xv.x, w0, acc[rr]);
      acc[rr] = fmaf(xv.y, w1, acc[rr]);
      acc[rr] = fmaf(xv.z, w2, acc[rr]);
      acc[rr] = fmaf(xv.w, w3, acc[rr]);
    }
  }

  const float bb = bred[lane], gg = gred[lane], be = betared[lane];
#pragma unroll
  for (int rr = 0; rr < 4; ++rr) {
    int gr = min(base + lr0 + rr, NROWS - 1);
    float y = fmaxf(acc[rr] + bb, 0.f);
    // LayerNorm over R=64 == one full wave
    float s = y;
#pragma unroll
    for (int m = 32; m >= 1; m >>= 1) s += __shfl_xor(s, m, 64);
    float mean = s * (1.f / 64.f);
    float td = y - mean;
    float v = td * td;
#pragma unroll
    for (int m = 32; m >= 1; m >>= 1) v += __shfl_xor(v, m, 64);
    v *= (1.f / 64.f);
    float cf = td * rsqrtf(v + 1e-5f) * gg + be;

    if (gr < NSAMP) {
      atomicMax(pp_u + b * 64 + lane, f2ord(cf));
    } else {
      int l = gr - NSAMP;
      present[((size_t)b * NPRES + l) * 64 + lane] = cf;
      if (l == NPRES - 1) out_now[b * 64 + lane] = cf;
    }
  }
}

// K3: one block per (b, l). Rebuild cummax prefix (cheap), then
// out = LN(ReLU(gm @ w_exp + b_exp)) over D=512 (2 outputs per thread).
__global__ __launch_bounds__(256) void k3_expand(
    const float* __restrict__ wexp, const float* __restrict__ bexp,
    const float* __restrict__ gexp, const float* __restrict__ betaexp,
    const unsigned* __restrict__ pp_u, const float* __restrict__ present,
    float* __restrict__ out_gm)       // [B][20][512]
{
  __shared__ float gm[64];
  __shared__ float red_s[4], red_s2[4];
  __shared__ float bc[2];
  const int l = blockIdx.x;   // 0..19
  const int b = blockIdx.y;
  const int tid = threadIdx.x;

  if (tid < 64) {
    float v = ord2f(pp_u[b * 64 + tid]);
    for (int j = 0; j <= l; ++j)
      v = fmaxf(v, present[((size_t)b * NPRES + j) * 64 + tid]);
    gm[tid] = v;
  }
  __syncthreads();

  const int d0 = tid, d1 = tid + 256;
  float a0 = 0.f, a1 = 0.f;
#pragma unroll 8
  for (int r = 0; r < Rdim; ++r) {
    float g = gm[r];
    a0 = fmaf(g, wexp[r * Ddim + d0], a0);
    a1 = fmaf(g, wexp[r * Ddim + d1], a1);
  }
  float y0 = fmaxf(a0 + bexp[d0], 0.f);
  float y1 = fmaxf(a1 + bexp[d1], 0.f);

  float s = y0 + y1, s2 = fmaf(y0, y0, y1 * y1);
#pragma unroll
  for (int m = 32; m >= 1; m >>= 1) {
    s  += __shfl_xor(s,  m, 64);
    s2 += __shfl_xor(s2, m, 64);
  }
  int wid = tid >> 6, lane = tid & 63;
  if (lane == 0) { red_s[wid] = s; red_s2[wid] = s2; }
  __syncthreads();
  if (tid == 0) {
    float S  = red_s[0] + red_s[1] + red_s[2] + red_s[3];
    float S2 = red_s2[0] + red_s2[1] + red_s2[2] + red_s2[3];
    float mean = S * (1.f / 512.f);
    float var  = S2 * (1.f / 512.f) - mean * mean;
    bc[0] = mean;
    bc[1] = rsqrtf(fmaxf(var, 0.f) + 1e-5f);
  }
  __syncthreads();
  float mean = bc[0], inv = bc[1];
  size_t o = ((size_t)b * NPRES + l) * Ddim;
  out_gm[o + d0] = (y0 - mean) * inv * gexp[d0] + betaexp[d0];
  out_gm[o + d1] = (y1 - mean) * inv * gexp[d1] + betaexp[d1];
}

extern "C" void kernel_launch(void* const* d_in, const int* in_sizes, int n_in,
                              void* d_out, int out_size, void* d_ws, size_t ws_size,
                              hipStream_t stream) {
  const float* obs     = (const float*)d_in[0];
  const float* wred    = (const float*)d_in[1];
  const float* bred    = (const float*)d_in[2];
  const float* gred    = (const float*)d_in[3];
  const float* betared = (const float*)d_in[4];
  const float* wexp    = (const float*)d_in[5];
  const float* bexp    = (const float*)d_in[6];
  const float* gexp    = (const float*)d_in[7];
  const float* betaexp = (const float*)d_in[8];

  float* out_gm  = (float*)d_out;                       // 32*20*512
  float* out_now = (float*)d_out + Bsz * NPRES * Ddim;  // 32*64

  unsigned* pp_u = (unsigned*)d_ws;                               // 8 KB
  float* present = (float*)((char*)d_ws + Bsz * 64 * sizeof(unsigned)); // 160 KB

  // Re-init the atomic-max buffer every call (0 == below -inf in our encoding).
  hipMemsetAsync(pp_u, 0, Bsz * 64 * sizeof(unsigned), stream);

  dim3 g1((NROWS + 15) / 16, Bsz);   // 27 x 32
  k1_cf<<<g1, 256, 0, stream>>>(obs, wred, bred, gred, betared,
                                pp_u, present, out_now);

  dim3 g3(NPRES, Bsz);               // 20 x 32
  k3_expand<<<g3, 256, 0, stream>>>(wexp, bexp, gexp, betaexp,
                                    pp_u, present, out_gm);
}

// Round 4
// 26.380 us; speedup vs baseline: 2.2061x; 2.2061x over previous
//
#include <hip/hip_runtime.h>

// B=32, T=4096, D=512, R=64, LOCAL_SIZE=20, SAMPLING_RATE=10, LN_EPS=1e-5
static constexpr int Bsz   = 32;
static constexpr int Tlen  = 4096;
static constexpr int Ddim  = 512;
static constexpr int NSAMP = 408;   // len(range(0, 4076, 10))
static constexpr int NPRES = 20;
static constexpr int NROWS = NSAMP + NPRES;  // 428
static constexpr int RPB   = 64;    // rows per k1 block
static constexpr int NBLK  = 7;     // ceil(428/64)

typedef __attribute__((ext_vector_type(8))) short short8;  // 8 bf16
typedef __attribute__((ext_vector_type(4))) float f32x4;

__device__ __forceinline__ unsigned short f2bf(float x) {
  union { float f; unsigned u; } c; c.f = x;
  unsigned r = c.u + 0x7FFFu + ((c.u >> 16) & 1u);   // RNE
  return (unsigned short)(r >> 16);
}

// XOR-swizzle: row-major [64][512] bf16 tile (1024 B rows). Without swizzle,
// 16 lanes reading 16 rows at the same col hit one bank (32-way-class
// conflict). XOR bits 4-6 of the col-byte with row&7 -> 8 distinct 16B
// slots -> 2-way (free). Applied on BOTH write and read (reg-staged).
__device__ __forceinline__ int swz(int row, int colByte) {
  return (row << 10) + (colByte ^ ((row & 7) << 4));
}

// K1: cf = LN(ReLU(obs_rows @ w_red + b_red)) for the 428 needed rows.
// MFMA 16x16x32 bf16; per block: 64 rows x 64 ch. Outputs: per-block
// sampled max (bpart), present rows, now row.
__global__ __launch_bounds__(256) void k1_cf(
    const float* __restrict__ obs, const float* __restrict__ wred,
    const float* __restrict__ bred, const float* __restrict__ gred,
    const float* __restrict__ betared,
    float* __restrict__ bpart,     // [B][NBLK][64]
    float* __restrict__ present,   // [B][20][64]
    float* __restrict__ out_now)   // [B][64]
{
  __shared__ short xs[RPB * Ddim];   // 64 KB bf16, swizzled [row][k]
  __shared__ short wt[64 * Ddim];    // 64 KB bf16, swizzled [ch][k]
  __shared__ float wmax[4][64];

  const int b    = blockIdx.y;
  const int bx   = blockIdx.x;
  const int base = bx * RPB;
  const int tid  = threadIdx.x;
  char* xsB = (char*)xs;
  char* wtB = (char*)wt;

  // ---- stage obs rows: f32 -> bf16 into xs (coalesced float4 reads) ----
  const float* obs_b = obs + (size_t)b * Tlen * Ddim;
#pragma unroll 8
  for (int it = 0; it < 32; ++it) {
    int u    = it * 256 + tid;        // 0..8191 = 64 rows * 128 float4
    int row  = u >> 7;
    int c4   = u & 127;
    int graw = base + row;
    int gr   = graw < NROWS ? graw : NROWS - 1;   // clamp: benign dup work
    int t    = gr < NSAMP ? gr * 10 : (Tlen - NPRES) + (gr - NSAMP);
    float4 v = *(const float4*)(obs_b + (size_t)t * Ddim + c4 * 4);
    uint2 wv;
    wv.x = (unsigned)f2bf(v.x) | ((unsigned)f2bf(v.y) << 16);
    wv.y = (unsigned)f2bf(v.z) | ((unsigned)f2bf(v.w) << 16);
    *(uint2*)(xsB + swz(row, c4 * 8)) = wv;
  }

  // ---- stage w_red^T: wred[512][64] f32 -> wt[ch][k] bf16 (transpose) ----
#pragma unroll 4
  for (int it = 0; it < 16; ++it) {
    int dp = it * 16 + (tid >> 4);    // k-pair index 0..255
    int d  = dp * 2;
    int r0 = (tid & 15) * 4;
    float4 va = *(const float4*)(wred + (size_t)d * 64 + r0);
    float4 vb = *(const float4*)(wred + (size_t)(d + 1) * 64 + r0);
    *(unsigned*)(wtB + swz(r0 + 0, d * 2)) =
        (unsigned)f2bf(va.x) | ((unsigned)f2bf(vb.x) << 16);
    *(unsigned*)(wtB + swz(r0 + 1, d * 2)) =
        (unsigned)f2bf(va.y) | ((unsigned)f2bf(vb.y) << 16);
    *(unsigned*)(wtB + swz(r0 + 2, d * 2)) =
        (unsigned)f2bf(va.z) | ((unsigned)f2bf(vb.z) << 16);
    *(unsigned*)(wtB + swz(r0 + 3, d * 2)) =
        (unsigned)f2bf(va.w) | ((unsigned)f2bf(vb.w) << 16);
  }
  __syncthreads();

  // ---- MFMA: wave w owns rows w*16..w*16+15, all 64 ch (4 ch-groups) ----
  const int w    = tid >> 6;
  const int lane = tid & 63;
  const int l15  = lane & 15;
  const int lhi  = lane >> 4;
  const int arow = w * 16 + l15;

  f32x4 acc0 = {0.f, 0.f, 0.f, 0.f};
  f32x4 acc1 = {0.f, 0.f, 0.f, 0.f};
  f32x4 acc2 = {0.f, 0.f, 0.f, 0.f};
  f32x4 acc3 = {0.f, 0.f, 0.f, 0.f};
#pragma unroll
  for (int ks = 0; ks < 16; ++ks) {
    int colB = ks * 64 + lhi * 16;    // byte offset of this lane's k-window
    short8 av  = *(const short8*)(xsB + swz(arow,     colB));
    short8 bv0 = *(const short8*)(wtB + swz(l15,      colB));
    short8 bv1 = *(const short8*)(wtB + swz(16 + l15, colB));
    short8 bv2 = *(const short8*)(wtB + swz(32 + l15, colB));
    short8 bv3 = *(const short8*)(wtB + swz(48 + l15, colB));
    acc0 = __builtin_amdgcn_mfma_f32_16x16x32_bf16(av, bv0, acc0, 0, 0, 0);
    acc1 = __builtin_amdgcn_mfma_f32_16x16x32_bf16(av, bv1, acc1, 0, 0, 0);
    acc2 = __builtin_amdgcn_mfma_f32_16x16x32_bf16(av, bv2, acc2, 0, 0, 0);
    acc3 = __builtin_amdgcn_mfma_f32_16x16x32_bf16(av, bv3, acc3, 0, 0, 0);
  }

  // ---- epilogue: bias+ReLU+LN per row; route to bpart/present/out_now ----
  const int ch0 = l15, ch1 = 16 + l15, ch2 = 32 + l15, ch3 = 48 + l15;
  const float bb0 = bred[ch0], bb1 = bred[ch1], bb2 = bred[ch2], bb3 = bred[ch3];
  const float gg0 = gred[ch0], gg1 = gred[ch1], gg2 = gred[ch2], gg3 = gred[ch3];
  const float be0 = betared[ch0], be1 = betared[ch1];
  const float be2 = betared[ch2], be3 = betared[ch3];
  float m0 = -INFINITY, m1 = -INFINITY, m2 = -INFINITY, m3 = -INFINITY;
  float* pres_b = present + (size_t)b * NPRES * 64;

#pragma unroll
  for (int q = 0; q < 4; ++q) {
    int rloc = lhi * 4 + q;                 // D row = (lane>>4)*4 + reg
    int graw = base + w * 16 + rloc;
    int gr   = graw < NROWS ? graw : NROWS - 1;
    float y0 = fmaxf(acc0[q] + bb0, 0.f);
    float y1 = fmaxf(acc1[q] + bb1, 0.f);
    float y2 = fmaxf(acc2[q] + bb2, 0.f);
    float y3 = fmaxf(acc3[q] + bb3, 0.f);
    float s  = y0 + y1 + y2 + y3;
    float s2 = y0 * y0 + y1 * y1 + y2 * y2 + y3 * y3;
#pragma unroll
    for (int msk = 1; msk <= 8; msk <<= 1) {
      s  += __shfl_xor(s,  msk, 64);
      s2 += __shfl_xor(s2, msk, 64);
    }
    float mean = s * (1.f / 64.f);
    float var  = s2 * (1.f / 64.f) - mean * mean;
    float inv  = rsqrtf(fmaxf(var, 0.f) + 1e-5f);
    float c0 = (y0 - mean) * inv * gg0 + be0;
    float c1 = (y1 - mean) * inv * gg1 + be1;
    float c2 = (y2 - mean) * inv * gg2 + be2;
    float c3 = (y3 - mean) * inv * gg3 + be3;
    if (gr < NSAMP) {
      m0 = fmaxf(m0, c0); m1 = fmaxf(m1, c1);
      m2 = fmaxf(m2, c2); m3 = fmaxf(m3, c3);
    } else {
      int l = gr - NSAMP;
      pres_b[l * 64 + ch0] = c0;  pres_b[l * 64 + ch1] = c1;
      pres_b[l * 64 + ch2] = c2;  pres_b[l * 64 + ch3] = c3;
      if (gr == NROWS - 1) {
        out_now[b * 64 + ch0] = c0;  out_now[b * 64 + ch1] = c1;
        out_now[b * 64 + ch2] = c2;  out_now[b * 64 + ch3] = c3;
      }
    }
  }

  // block-level sampled max -> bpart (no atomics; deterministic)
  m0 = fmaxf(m0, __shfl_xor(m0, 16, 64)); m0 = fmaxf(m0, __shfl_xor(m0, 32, 64));
  m1 = fmaxf(m1, __shfl_xor(m1, 16, 64)); m1 = fmaxf(m1, __shfl_xor(m1, 32, 64));
  m2 = fmaxf(m2, __shfl_xor(m2, 16, 64)); m2 = fmaxf(m2, __shfl_xor(m2, 32, 64));
  m3 = fmaxf(m3, __shfl_xor(m3, 16, 64)); m3 = fmaxf(m3, __shfl_xor(m3, 32, 64));
  if (lhi == 0) {
    wmax[w][ch0] = m0; wmax[w][ch1] = m1; wmax[w][ch2] = m2; wmax[w][ch3] = m3;
  }
  __syncthreads();
  if (tid < 64) {
    float m = fmaxf(fmaxf(wmax[0][tid], wmax[1][tid]),
                    fmaxf(wmax[2][tid], wmax[3][tid]));
    bpart[((size_t)b * NBLK + bx) * 64 + tid] = m;
  }
}

// K3: one block per (b, l). gm = max(bpart[0..6], present[0..l]) computed
// wave-parallel; then out = LN(ReLU(gm @ w_exp + b_exp)) over D=512.
__global__ __launch_bounds__(256) void k3_expand(
    const float* __restrict__ wexp, const float* __restrict__ bexp,
    const float* __restrict__ gexp, const float* __restrict__ betaexp,
    const float* __restrict__ bpart, const float* __restrict__ present,
    float* __restrict__ out_gm)      // [B][20][512]
{
  __shared__ float part[4][64];
  __shared__ float gm[64];
  __shared__ float red_s[4], red_s2[4];
  __shared__ float bc[2];
  const int l = blockIdx.x;   // 0..19
  const int b = blockIdx.y;
  const int tid = threadIdx.x;
  const int r = tid & 63, j = tid >> 6;

  const int nsrc = NBLK + l + 1;     // 7 block-partials + l+1 present rows
  float v = -INFINITY;
  for (int s = j; s < nsrc; s += 4)
    v = fmaxf(v, s < NBLK ? bpart[((size_t)b * NBLK + s) * 64 + r]
                          : present[((size_t)b * NPRES + (s - NBLK)) * 64 + r]);
  part[j][r] = v;
  __syncthreads();
  if (tid < 64)
    gm[tid] = fmaxf(fmaxf(part[0][tid], part[1][tid]),
                    fmaxf(part[2][tid], part[3][tid]));
  __syncthreads();

  const int d0 = tid, d1 = tid + 256;
  float a0 = 0.f, a1 = 0.f;
#pragma unroll 8
  for (int rr = 0; rr < 64; ++rr) {
    float g = gm[rr];
    a0 = fmaf(g, wexp[rr * Ddim + d0], a0);
    a1 = fmaf(g, wexp[rr * Ddim + d1], a1);
  }
  float y0 = fmaxf(a0 + bexp[d0], 0.f);
  float y1 = fmaxf(a1 + bexp[d1], 0.f);

  float s = y0 + y1, s2 = fmaf(y0, y0, y1 * y1);
#pragma unroll
  for (int m = 32; m >= 1; m >>= 1) {
    s  += __shfl_xor(s,  m, 64);
    s2 += __shfl_xor(s2, m, 64);
  }
  int wid = tid >> 6, lane = tid & 63;
  if (lane == 0) { red_s[wid] = s; red_s2[wid] = s2; }
  __syncthreads();
  if (tid == 0) {
    float S  = red_s[0] + red_s[1] + red_s[2] + red_s[3];
    float S2 = red_s2[0] + red_s2[1] + red_s2[2] + red_s2[3];
    float mean = S * (1.f / 512.f);
    float var  = S2 * (1.f / 512.f) - mean * mean;
    bc[0] = mean;
    bc[1] = rsqrtf(fmaxf(var, 0.f) + 1e-5f);
  }
  __syncthreads();
  float mean = bc[0], inv = bc[1];
  size_t o = ((size_t)b * NPRES + l) * Ddim;
  out_gm[o + d0] = (y0 - mean) * inv * gexp[d0] + betaexp[d0];
  out_gm[o + d1] = (y1 - mean) * inv * gexp[d1] + betaexp[d1];
}

extern "C" void kernel_launch(void* const* d_in, const int* in_sizes, int n_in,
                              void* d_out, int out_size, void* d_ws, size_t ws_size,
                              hipStream_t stream) {
  const float* obs     = (const float*)d_in[0];
  const float* wred    = (const float*)d_in[1];
  const float* bred    = (const float*)d_in[2];
  const float* gred    = (const float*)d_in[3];
  const float* betared = (const float*)d_in[4];
  const float* wexp    = (const float*)d_in[5];
  const float* bexp    = (const float*)d_in[6];
  const float* gexp    = (const float*)d_in[7];
  const float* betaexp = (const float*)d_in[8];

  float* out_gm  = (float*)d_out;                       // 32*20*512
  float* out_now = (float*)d_out + Bsz * NPRES * Ddim;  // 32*64

  float* bpart   = (float*)d_ws;                        // 32*7*64 = 57 KB
  float* present = bpart + Bsz * NBLK * 64;             // 32*20*64 = 160 KB

  dim3 g1(NBLK, Bsz);                // 7 x 32 = 224 blocks
  k1_cf<<<g1, 256, 0, stream>>>(obs, wred, bred, gred, betared,
                                bpart, present, out_now);

  dim3 g3(NPRES, Bsz);               // 20 x 32 = 640 blocks
  k3_expand<<<g3, 256, 0, stream>>>(wexp, bexp, gexp, betaexp,
                                    bpart, present, out_gm);
}

// Round 5
// 22.310 us; speedup vs baseline: 2.6086x; 1.1824x over previous
//
#include <hip/hip_runtime.h>

// B=32, T=4096, D=512, R=64, LOCAL_SIZE=20, SAMPLING_RATE=10, LN_EPS=1e-5
static constexpr int Bsz   = 32;
static constexpr int Tlen  = 4096;
static constexpr int Ddim  = 512;
static constexpr int NSAMP = 408;   // len(range(0, 4076, 10))
static constexpr int NPRES = 20;
static constexpr int NROWS = NSAMP + NPRES;  // 428
static constexpr int RPB   = 64;    // rows per k1 block
static constexpr int NBLK  = 7;     // ceil(428/64)

typedef __attribute__((ext_vector_type(8))) short short8;  // 8 bf16
typedef __attribute__((ext_vector_type(4))) float f32x4;

__device__ __forceinline__ unsigned short f2bf(float x) {
  union { float f; unsigned u; } c; c.f = x;
  unsigned r = c.u + 0x7FFFu + ((c.u >> 16) & 1u);   // RNE
  return (unsigned short)(r >> 16);
}

// XOR-swizzle for row-major [64][512] bf16 tiles (1024 B rows): 16 lanes
// reading 16 rows at one col-window would all hit the same bank. XOR bits
// 4-6 of the col-byte with row&7 -> 8 distinct 16B slots -> 2-way (free).
// Applied on BOTH LDS write and read (reg-staged staging, so legal).
__device__ __forceinline__ int swz(int row, int colByte) {
  return (row << 10) + (colByte ^ ((row & 7) << 4));
}

// K1: cf = LN(ReLU(obs_rows @ w_red + b_red)) for the 428 needed rows.
// 1024 threads = 16 waves: wave w owns rows (w&3)*16..+15 and chs
// (w>>2)*16..+15 (one 16x16x32 MFMA chain). LN over 64 chs = in-wave
// 16-lane shuffle partial + 4-way cross-wave LDS reduce.
__global__ __launch_bounds__(1024) void k1_cf(
    const float* __restrict__ obs, const float* __restrict__ wred,
    const float* __restrict__ bred, const float* __restrict__ gred,
    const float* __restrict__ betared,
    float* __restrict__ bpart,     // [B][NBLK][64]
    float* __restrict__ present,   // [B][20][64]
    float* __restrict__ out_now)   // [B][64]
{
  __shared__ short xs[RPB * Ddim];     // 64 KB bf16, swizzled [row][k]
  __shared__ short wt[64 * Ddim];      // 64 KB bf16, swizzled [ch][k]
  __shared__ float sred[64][4];        // per-row, per-ch-group sum partials
  __shared__ float s2red[64][4];
  __shared__ float wmax[4][64];        // per-row-group sampled max

  const int b    = blockIdx.y;
  const int bx   = blockIdx.x;
  const int base = bx * RPB;
  const int tid  = threadIdx.x;
  char* xsB = (char*)xs;
  char* wtB = (char*)wt;

  // ---- stage obs rows: f32 -> bf16 into xs (coalesced float4 reads) ----
  const float* obs_b = obs + (size_t)b * Tlen * Ddim;
#pragma unroll
  for (int it = 0; it < 8; ++it) {
    int u    = it * 1024 + tid;       // 0..8191 = 64 rows * 128 float4
    int row  = u >> 7;
    int c4   = u & 127;
    int graw = base + row;
    int gr   = graw < NROWS ? graw : NROWS - 1;   // clamp: benign dup work
    int t    = gr < NSAMP ? gr * 10 : (Tlen - NPRES) + (gr - NSAMP);
    float4 v = *(const float4*)(obs_b + (size_t)t * Ddim + c4 * 4);
    uint2 wv;
    wv.x = (unsigned)f2bf(v.x) | ((unsigned)f2bf(v.y) << 16);
    wv.y = (unsigned)f2bf(v.z) | ((unsigned)f2bf(v.w) << 16);
    *(uint2*)(xsB + swz(row, c4 * 8)) = wv;
  }

  // ---- stage w_red^T: wred[512][64] f32 -> wt[ch][k] bf16 (transpose) ----
#pragma unroll
  for (int it = 0; it < 4; ++it) {
    int dp = it * 64 + (tid >> 4);    // k-pair index 0..255
    int d  = dp * 2;
    int r0 = (tid & 15) * 4;
    float4 va = *(const float4*)(wred + (size_t)d * 64 + r0);
    float4 vb = *(const float4*)(wred + (size_t)(d + 1) * 64 + r0);
    *(unsigned*)(wtB + swz(r0 + 0, d * 2)) =
        (unsigned)f2bf(va.x) | ((unsigned)f2bf(vb.x) << 16);
    *(unsigned*)(wtB + swz(r0 + 1, d * 2)) =
        (unsigned)f2bf(va.y) | ((unsigned)f2bf(vb.y) << 16);
    *(unsigned*)(wtB + swz(r0 + 2, d * 2)) =
        (unsigned)f2bf(va.z) | ((unsigned)f2bf(vb.z) << 16);
    *(unsigned*)(wtB + swz(r0 + 3, d * 2)) =
        (unsigned)f2bf(va.w) | ((unsigned)f2bf(vb.w) << 16);
  }
  __syncthreads();

  // ---- MFMA: wave w -> row-group w&3, ch-group w>>2 ----
  const int w    = tid >> 6;
  const int lane = tid & 63;
  const int l15  = lane & 15;
  const int lhi  = lane >> 4;
  const int rowg = w & 3;
  const int chg  = w >> 2;
  const int arow = rowg * 16 + l15;
  const int brow = chg * 16 + l15;

  f32x4 acc = {0.f, 0.f, 0.f, 0.f};
#pragma unroll
  for (int ks = 0; ks < 16; ++ks) {
    int colB = ks * 64 + lhi * 16;    // byte offset of this lane's k-window
    short8 av = *(const short8*)(xsB + swz(arow, colB));
    short8 bv = *(const short8*)(wtB + swz(brow, colB));
    acc = __builtin_amdgcn_mfma_f32_16x16x32_bf16(av, bv, acc, 0, 0, 0);
  }

  // ---- epilogue: bias+ReLU, cross-wave LN, route outputs ----
  // C/D layout (m89-verified): ch (B free dim) = lane&15, obs row (A free
  // dim) = (lane>>4)*4 + q.
  const int c  = chg * 16 + l15;
  const float bb = bred[c], gg = gred[c], be = betared[c];
  float y[4];
#pragma unroll
  for (int q = 0; q < 4; ++q) {
    y[q] = fmaxf(acc[q] + bb, 0.f);
    float s = y[q], s2 = y[q] * y[q];
#pragma unroll
    for (int msk = 1; msk <= 8; msk <<= 1) {
      s  += __shfl_xor(s,  msk, 64);
      s2 += __shfl_xor(s2, msk, 64);
    }
    if (l15 == 0) {
      int grow = rowg * 16 + lhi * 4 + q;
      sred[grow][chg]  = s;
      s2red[grow][chg] = s2;
    }
  }
  __syncthreads();

  float m = -INFINITY;
  float* pres_b = present + (size_t)b * NPRES * 64;
#pragma unroll
  for (int q = 0; q < 4; ++q) {
    int grow = rowg * 16 + lhi * 4 + q;
    float S  = sred[grow][0] + sred[grow][1] + sred[grow][2] + sred[grow][3];
    float S2 = s2red[grow][0] + s2red[grow][1] + s2red[grow][2] + s2red[grow][3];
    float mean = S * (1.f / 64.f);
    float var  = S2 * (1.f / 64.f) - mean * mean;
    float inv  = rsqrtf(fmaxf(var, 0.f) + 1e-5f);
    float cf   = (y[q] - mean) * inv * gg + be;
    int graw = base + grow;
    int gr   = graw < NROWS ? graw : NROWS - 1;
    if (gr < NSAMP) {
      m = fmaxf(m, cf);
    } else {
      int l = gr - NSAMP;
      pres_b[l * 64 + c] = cf;
      if (gr == NROWS - 1) out_now[b * 64 + c] = cf;
    }
  }

  // block-level sampled max -> bpart (no atomics; deterministic)
  m = fmaxf(m, __shfl_xor(m, 16, 64));
  m = fmaxf(m, __shfl_xor(m, 32, 64));
  if (lhi == 0) wmax[rowg][c] = m;
  __syncthreads();
  if (tid < 64) {
    float mm = fmaxf(fmaxf(wmax[0][tid], wmax[1][tid]),
                     fmaxf(wmax[2][tid], wmax[3][tid]));
    bpart[((size_t)b * NBLK + bx) * 64 + tid] = mm;
  }
}

// K3: one block per (b, l-pair). Each w_exp read feeds 4 FMAs (2 l's x
// 2 d's) -> half the L2 re-streaming of the 1-l version.
__global__ __launch_bounds__(256) void k3_expand(
    const float* __restrict__ wexp, const float* __restrict__ bexp,
    const float* __restrict__ gexp, const float* __restrict__ betaexp,
    const float* __restrict__ bpart, const float* __restrict__ present,
    float* __restrict__ out_gm)      // [B][20][512]
{
  __shared__ float partA[4][64], partB[4][64];
  __shared__ float gm0[64], gm1[64];
  __shared__ float red_s[2][4], red_s2[2][4];
  __shared__ float bc[2][2];
  const int l0 = blockIdx.x * 2, l1 = l0 + 1;
  const int b  = blockIdx.y;
  const int tid = threadIdx.x;
  const int r = tid & 63, j = tid >> 6;

  const int n0 = NBLK + l0 + 1;      // sources for l0
  const int n1 = n0 + 1;             // sources for l1
  float vA = -INFINITY, vB = -INFINITY;
  for (int s = j; s < n1; s += 4) {
    float x = s < NBLK ? bpart[((size_t)b * NBLK + s) * 64 + r]
                       : present[((size_t)b * NPRES + (s - NBLK)) * 64 + r];
    vB = fmaxf(vB, x);
    if (s < n0) vA = fmaxf(vA, x);
  }
  partA[j][r] = vA;
  partB[j][r] = vB;
  __syncthreads();
  if (tid < 64) {
    gm0[tid] = fmaxf(fmaxf(partA[0][tid], partA[1][tid]),
                     fmaxf(partA[2][tid], partA[3][tid]));
  } else if (tid < 128) {
    int t = tid - 64;
    gm1[t] = fmaxf(fmaxf(partB[0][t], partB[1][t]),
                   fmaxf(partB[2][t], partB[3][t]));
  }
  __syncthreads();

  const int d0 = tid, d1 = tid + 256;
  float a00 = 0.f, a01 = 0.f, a10 = 0.f, a11 = 0.f;
#pragma unroll 8
  for (int rr = 0; rr < 64; ++rr) {
    float g0 = gm0[rr], g1 = gm1[rr];
    float w0 = wexp[rr * Ddim + d0], w1 = wexp[rr * Ddim + d1];
    a00 = fmaf(g0, w0, a00);  a01 = fmaf(g0, w1, a01);
    a10 = fmaf(g1, w0, a10);  a11 = fmaf(g1, w1, a11);
  }
  const float bx0 = bexp[d0], bx1 = bexp[d1];
  float y00 = fmaxf(a00 + bx0, 0.f), y01 = fmaxf(a01 + bx1, 0.f);
  float y10 = fmaxf(a10 + bx0, 0.f), y11 = fmaxf(a11 + bx1, 0.f);

  float s0 = y00 + y01, s20 = fmaf(y00, y00, y01 * y01);
  float s1 = y10 + y11, s21 = fmaf(y10, y10, y11 * y11);
#pragma unroll
  for (int msk = 32; msk >= 1; msk >>= 1) {
    s0  += __shfl_xor(s0,  msk, 64);
    s20 += __shfl_xor(s20, msk, 64);
    s1  += __shfl_xor(s1,  msk, 64);
    s21 += __shfl_xor(s21, msk, 64);
  }
  int wid = tid >> 6, lane = tid & 63;
  if (lane == 0) {
    red_s[0][wid] = s0;  red_s2[0][wid] = s20;
    red_s[1][wid] = s1;  red_s2[1][wid] = s21;
  }
  __syncthreads();
  if (tid == 0) {
#pragma unroll
    for (int ll = 0; ll < 2; ++ll) {
      float S  = red_s[ll][0] + red_s[ll][1] + red_s[ll][2] + red_s[ll][3];
      float S2 = red_s2[ll][0] + red_s2[ll][1] + red_s2[ll][2] + red_s2[ll][3];
      float mean = S * (1.f / 512.f);
      float var  = S2 * (1.f / 512.f) - mean * mean;
      bc[ll][0] = mean;
      bc[ll][1] = rsqrtf(fmaxf(var, 0.f) + 1e-5f);
    }
  }
  __syncthreads();
  const float g0c = gexp[d0], g1c = gexp[d1];
  const float be0 = betaexp[d0], be1 = betaexp[d1];
  size_t o0 = ((size_t)b * NPRES + l0) * Ddim;
  size_t o1 = ((size_t)b * NPRES + l1) * Ddim;
  out_gm[o0 + d0] = (y00 - bc[0][0]) * bc[0][1] * g0c + be0;
  out_gm[o0 + d1] = (y01 - bc[0][0]) * bc[0][1] * g1c + be1;
  out_gm[o1 + d0] = (y10 - bc[1][0]) * bc[1][1] * g0c + be0;
  out_gm[o1 + d1] = (y11 - bc[1][0]) * bc[1][1] * g1c + be1;
}

extern "C" void kernel_launch(void* const* d_in, const int* in_sizes, int n_in,
                              void* d_out, int out_size, void* d_ws, size_t ws_size,
                              hipStream_t stream) {
  const float* obs     = (const float*)d_in[0];
  const float* wred    = (const float*)d_in[1];
  const float* bred    = (const float*)d_in[2];
  const float* gred    = (const float*)d_in[3];
  const float* betared = (const float*)d_in[4];
  const float* wexp    = (const float*)d_in[5];
  const float* bexp    = (const float*)d_in[6];
  const float* gexp    = (const float*)d_in[7];
  const float* betaexp = (const float*)d_in[8];

  float* out_gm  = (float*)d_out;                       // 32*20*512
  float* out_now = (float*)d_out + Bsz * NPRES * Ddim;  // 32*64

  float* bpart   = (float*)d_ws;                        // 32*7*64
  float* present = bpart + Bsz * NBLK * 64;             // 32*20*64

  dim3 g1(NBLK, Bsz);                // 7 x 32 = 224 blocks, 1024 thr
  k1_cf<<<g1, 1024, 0, stream>>>(obs, wred, bred, gred, betared,
                                 bpart, present, out_now);

  dim3 g3(NPRES / 2, Bsz);           // 10 x 32 = 320 blocks
  k3_expand<<<g3, 256, 0, stream>>>(wexp, bexp, gexp, betaexp,
                                    bpart, present, out_gm);
}